// Round 1
// baseline (99.797 us; speedup 1.0000x reference)
//
#include <hip/hip_runtime.h>

// SPN left-to-right propagation: h[:, :, i, t] =
//   (1-g1-g2-g3)*x[...,i,t] + g1*h[...,i-1,t-1] + g2*h[...,i,t-1] + g3*h[...,i+1,t-1]
// Gates pre-normalized elementwise: if |G1|+|G2|+|G3| >= 1, divide by the sum.
//
// Shapes: [B=8, C=32, H=256, W=256] fp32. One workgroup per (b,c) plane,
// thread i = row i. Coefficients are lane-private (each thread reads its own
// row); only the h-neighbor exchange uses LDS (double-buffered, stride-1,
// conflict-free). Raw s_barrier + lgkmcnt(0) (NOT __syncthreads) so the
// one-chunk-ahead global prefetch stays in flight across the 16 per-chunk
// barriers (avoids the vmcnt(0) drain the compiler emits for __syncthreads).

#define HH 256
#define WW 256
#define CHUNK 16
#define NCHUNK (WW / CHUNK)

#define ELEM(v, k) ((k) == 0 ? (v).x : ((k) == 1 ? (v).y : ((k) == 2 ? (v).z : (v).w)))

extern "C" __global__ void __launch_bounds__(256, 1)
spn_lr_kernel(const float* __restrict__ xg, const float* __restrict__ g1g,
              const float* __restrict__ g2g, const float* __restrict__ g3g,
              float* __restrict__ outg) {
    const int tid = threadIdx.x;  // row index i
    const size_t rowbase = (size_t)blockIdx.x * (size_t)(HH * WW) + (size_t)tid * WW;
    const float4* px = reinterpret_cast<const float4*>(xg + rowbase);
    const float4* p1 = reinterpret_cast<const float4*>(g1g + rowbase);
    const float4* p2 = reinterpret_cast<const float4*>(g2g + rowbase);
    const float4* p3 = reinterpret_cast<const float4*>(g3g + rowbase);
    float4* po = reinterpret_cast<float4*>(outg + rowbase);

    // h exchange buffers, padded: index j+1 holds row j; [0] and [HH+1] stay 0.
    __shared__ float hb0[HH + 2];
    __shared__ float hb1[HH + 2];
    hb0[tid + 1] = 0.0f;
    hb1[tid + 1] = 0.0f;
    if (tid == 0) {
        hb0[0] = 0.0f; hb1[0] = 0.0f;
        hb0[HH + 1] = 0.0f; hb1[HH + 1] = 0.0f;
    }
    __syncthreads();

    // Prefetch chunk 0 (raw, un-normalized).
    float4 nx[4], n1[4], n2[4], n3[4];
#pragma unroll
    for (int j = 0; j < 4; ++j) {
        nx[j] = px[j]; n1[j] = p1[j]; n2[j] = p2[j]; n3[j] = p3[j];
    }

    float h = 0.0f;  // h_prev for this row

#pragma unroll 1
    for (int tc = 0; tc < NCHUNK; ++tc) {
        // ---- normalize current chunk's gates into scalar regs (consumes nx/n*) ----
        float xs[CHUNK], as[CHUNK], c1[CHUNK], c2[CHUNK], c3[CHUNK];
#pragma unroll
        for (int j = 0; j < 4; ++j) {
            float4 vx = nx[j], v1 = n1[j], v2 = n2[j], v3 = n3[j];
#pragma unroll
            for (int k = 0; k < 4; ++k) {
                const int s = j * 4 + k;
                float A1 = ELEM(v1, k), A2 = ELEM(v2, k), A3 = ELEM(v3, k);
                float sa = fabsf(A1) + fabsf(A2) + fabsf(A3);
                sa = (sa == 0.0f) ? 1e-6f : sa;
                const float inv = 1.0f / sa;
                const bool m = (sa >= 1.0f);
                const float B1 = m ? A1 * inv : A1;
                const float B2 = m ? A2 * inv : A2;
                const float B3 = m ? A3 * inv : A3;
                xs[s] = ELEM(vx, k);
                c1[s] = B1; c2[s] = B2; c3[s] = B3;
                as[s] = 1.0f - B1 - B2 - B3;
            }
        }

        // ---- issue prefetch for next chunk; stays in flight across barriers ----
        if (tc + 1 < NCHUNK) {
            const int o = (tc + 1) * 4;
#pragma unroll
            for (int j = 0; j < 4; ++j) {
                nx[j] = px[o + j]; n1[j] = p1[o + j];
                n2[j] = p2[o + j]; n3[j] = p3[o + j];
            }
        }

        // ---- 16 recurrence steps; one raw barrier each ----
        float ho[CHUNK];
#pragma unroll
        for (int s = 0; s < CHUNK; ++s) {
            // global step parity: CHUNK is even, so parity == s & 1 every chunk
            const float* rb = (s & 1) ? hb1 : hb0;
            float* wb = (s & 1) ? hb0 : hb1;
            const float up = rb[tid];       // h_prev[i-1] (padded: +1 shift)
            const float dn = rb[tid + 2];   // h_prev[i+1]
            const float hn = as[s] * xs[s] + c1[s] * up + c2[s] * h + c3[s] * dn;
            wb[tid + 1] = hn;
            ho[s] = hn;
            h = hn;
            // LDS writes visible, then sync; do NOT drain vmcnt (prefetch in flight)
            asm volatile("s_waitcnt lgkmcnt(0)" ::: "memory");
            __builtin_amdgcn_s_barrier();
            asm volatile("" ::: "memory");
        }

        // ---- store this chunk's outputs (row-contiguous, 4x float4) ----
#pragma unroll
        for (int j = 0; j < 4; ++j) {
            float4 v;
            v.x = ho[j * 4 + 0]; v.y = ho[j * 4 + 1];
            v.z = ho[j * 4 + 2]; v.w = ho[j * 4 + 3];
            po[tc * 4 + j] = v;
        }
    }
}

extern "C" void kernel_launch(void* const* d_in, const int* in_sizes, int n_in,
                              void* d_out, int out_size, void* d_ws, size_t ws_size,
                              hipStream_t stream) {
    const float* x  = (const float*)d_in[0];
    const float* G1 = (const float*)d_in[1];
    const float* G2 = (const float*)d_in[2];
    const float* G3 = (const float*)d_in[3];
    float* out = (float*)d_out;

    const int nplanes = in_sizes[0] / (HH * WW);  // B*C = 256
    spn_lr_kernel<<<dim3(nplanes), dim3(HH), 0, stream>>>(x, G1, G2, G3, out);
}